// Round 1
// baseline (194.855 us; speedup 1.0000x reference)
//
#include <hip/hip_runtime.h>
#include <hip/hip_bf16.h>

typedef __attribute__((ext_vector_type(8)))  short  short8;
typedef __attribute__((ext_vector_type(4)))  float  f32x4;
typedef __attribute__((ext_vector_type(16))) float  f32x16;

#define DEVINL static __device__ __forceinline__

constexpr int BATCH = 8;
constexpr int SEQ   = 4096;
constexpr int EMB   = 256;
constexpr int HD    = 128;

// (1/sqrt(HD)) * log2(e): softmax computed in exp2 domain
#define CSCALE 0.1275174475f

DEVINL unsigned cvt_pk_bf16(float lo, float hi) {
  unsigned r;
  asm("v_cvt_pk_bf16_f32 %0, %1, %2" : "=v"(r) : "v"(lo), "v"(hi));
  return r;
}

// v_permlane32_swap_b32: new_a[32+i] = old_b[i]; new_b[i] = old_a[32+i]
DEVINL void permswap32(unsigned &a, unsigned &b) {
  asm("v_permlane32_swap_b32 %0, %1" : "+v"(a), "+v"(b));
}

DEVINL short8 mk_frag(unsigned w0, unsigned w1, unsigned w2, unsigned w3) {
  union { unsigned u[4]; short8 s; } t;
  t.u[0] = w0; t.u[1] = w1; t.u[2] = w2; t.u[3] = w3;
  return t.s;
}

// ---------------------------------------------------------------------------
// Kernel 1: QKV projection.  out[s][h] = sum_e X[s][e] * W[h][e] + bias[h]
// which = blockIdx.y: 0->Q (row-major bf16), 1->K (row-major bf16),
//                     2->V stored TRANSPOSED as Vt[b][h][s] bf16.
// Block: 256 thr = 4 waves in 2x2; block tile 64 rows x 128 cols, K=256.
// ---------------------------------------------------------------------------
__global__ __launch_bounds__(256) void qkv_proj_kernel(
    const float* __restrict__ X,
    const float* __restrict__ Wq, const float* __restrict__ bq,
    const float* __restrict__ Wk, const float* __restrict__ bk,
    const float* __restrict__ Wv, const float* __restrict__ bv,
    __hip_bfloat16* __restrict__ Qw,
    __hip_bfloat16* __restrict__ Kw,
    __hip_bfloat16* __restrict__ Vt)
{
  const int which = blockIdx.y;
  const float* W   = which == 0 ? Wq : which == 1 ? Wk : Wv;
  const float* bia = which == 0 ? bq : which == 1 ? bk : bv;

  const int m0   = blockIdx.x * 64;
  const int tid  = threadIdx.x;
  const int wid  = tid >> 6;
  const int lane = tid & 63;
  const int wr   = wid >> 1, wc = wid & 1;
  const int l15  = lane & 15, l4 = lane >> 4;

  f32x4 acc[2][4];
#pragma unroll
  for (int qt = 0; qt < 2; ++qt)
#pragma unroll
    for (int nt = 0; nt < 4; ++nt)
#pragma unroll
      for (int r = 0; r < 4; ++r) acc[qt][nt][r] = 0.f;

  const int arow = m0 + wr * 32 + l15;      // + qt*16
  const int hrow = wc * 64 + l15;           // + nt*16

#pragma unroll
  for (int es = 0; es < 8; ++es) {          // K slices of 32
    const int k0 = es * 32 + l4 * 8;
    short8 af[2];
#pragma unroll
    for (int qt = 0; qt < 2; ++qt) {
      const float* src = X + (size_t)(arow + qt * 16) * EMB + k0;
      float4 f0 = *(const float4*)(src);
      float4 f1 = *(const float4*)(src + 4);
      af[qt] = mk_frag(cvt_pk_bf16(f0.x, f0.y), cvt_pk_bf16(f0.z, f0.w),
                       cvt_pk_bf16(f1.x, f1.y), cvt_pk_bf16(f1.z, f1.w));
    }
    short8 bf[4];
#pragma unroll
    for (int nt = 0; nt < 4; ++nt) {
      const float* src = W + (size_t)(hrow + nt * 16) * EMB + k0;
      float4 f0 = *(const float4*)(src);
      float4 f1 = *(const float4*)(src + 4);
      bf[nt] = mk_frag(cvt_pk_bf16(f0.x, f0.y), cvt_pk_bf16(f0.z, f0.w),
                       cvt_pk_bf16(f1.x, f1.y), cvt_pk_bf16(f1.z, f1.w));
    }
#pragma unroll
    for (int qt = 0; qt < 2; ++qt)
#pragma unroll
      for (int nt = 0; nt < 4; ++nt)
        acc[qt][nt] = __builtin_amdgcn_mfma_f32_16x16x32_bf16(
            af[qt], bf[nt], acc[qt][nt], 0, 0, 0);
  }

  // C layout (16x16x32): col = lane&15, row = (lane>>4)*4 + reg
#pragma unroll
  for (int qt = 0; qt < 2; ++qt) {
#pragma unroll
    for (int nt = 0; nt < 4; ++nt) {
      const int h    = wc * 64 + nt * 16 + l15;
      const float bb = bia[h];
      const int srow = m0 + wr * 32 + qt * 16 + l4 * 4;
      if (which != 2) {
        __hip_bfloat16* dst = (which == 0 ? Qw : Kw);
#pragma unroll
        for (int r = 0; r < 4; ++r)
          dst[(size_t)(srow + r) * HD + h] = __float2bfloat16(acc[qt][nt][r] + bb);
      } else {
        const int bi = srow >> 12;          // batch (tiles never cross: 4096%64==0)
        const int s  = srow & (SEQ - 1);
        unsigned w0 = cvt_pk_bf16(acc[qt][nt][0] + bb, acc[qt][nt][1] + bb);
        unsigned w1 = cvt_pk_bf16(acc[qt][nt][2] + bb, acc[qt][nt][3] + bb);
        unsigned long long pk = ((unsigned long long)w1 << 32) | (unsigned long long)w0;
        *(unsigned long long*)(Vt + ((size_t)bi * HD + h) * SEQ + s) = pk;
      }
    }
  }
}

// ---------------------------------------------------------------------------
// Kernel 2: flash attention.  4 waves x 32 q-rows (QBLK=128), KVBLK=64.
// Swapped QK^T: S^T[k][q] = mfma(A=K, B=Q^T)  -> lane owns q = lane&31.
// PV swapped:   O^T[d][q] = mfma(A=V^T, B=P^T) -> O on same lanes as stats.
// K LDS [64][128] and V^T LDS [128][64], both XOR-swizzled (row&7)<<4.
// ---------------------------------------------------------------------------
__global__ __launch_bounds__(256) void fused_attn_kernel(
    const __hip_bfloat16* __restrict__ Qw,
    const __hip_bfloat16* __restrict__ Kw,
    const __hip_bfloat16* __restrict__ Vt,
    float* __restrict__ out)
{
  __shared__ short8 sKbuf[64 * 128 / 8];   // 16 KB
  __shared__ short8 sVbuf[128 * 64 / 8];   // 16 KB
  char* sK = (char*)sKbuf;
  char* sV = (char*)sVbuf;

  const int tid  = threadIdx.x;
  const int wid  = tid >> 6;
  const int lane = tid & 63;
  const int l31  = lane & 31;
  const int hi   = lane >> 5;

  const int b  = blockIdx.x & 7;           // batch on low bits -> XCD-local K/V
  const int q0 = (blockIdx.x >> 3) * 128;

  const int qrow = q0 + wid * 32 + l31;

  const __hip_bfloat16* Qp = Qw + ((size_t)b * SEQ + qrow) * HD;
  const __hip_bfloat16* Kg = Kw + (size_t)b * SEQ * HD;
  const __hip_bfloat16* Vg = Vt + (size_t)b * HD * SEQ;

  // Q as B-operand frags (32x32x16): col=q=lane&31, k = hi*8 + j, slice es
  short8 qf[8];
#pragma unroll
  for (int es = 0; es < 8; ++es)
    qf[es] = *(const short8*)(Qp + es * 16 + hi * 8);

  f32x16 oacc[4];
#pragma unroll
  for (int dt = 0; dt < 4; ++dt)
#pragma unroll
    for (int r = 0; r < 16; ++r) oacc[dt][r] = 0.f;

  float m = -1e30f, l = 0.f;

  const int tK_r = tid >> 4, tK_c = (tid & 15) * 8;   // K stage: 16 thr/row
  const int tV_d = tid >> 3, tV_c = (tid & 7) * 8;    // V stage: 8 thr/row

  short8 rk[4], rv[4];
#pragma unroll
  for (int p = 0; p < 4; ++p) {            // prologue: tile 0 into regs
    rk[p] = *(const short8*)(Kg + (size_t)(p * 16 + tK_r) * HD + tK_c);
    rv[p] = *(const short8*)(Vg + (size_t)(p * 32 + tV_d) * SEQ + tV_c);
  }

  const int NT = SEQ / 64;
  const unsigned kswz = (unsigned)((l31 & 7) << 4);

  for (int kt = 0; kt < NT; ++kt) {
    __syncthreads();
#pragma unroll
    for (int p = 0; p < 4; ++p) {
      const int r = p * 16 + tK_r;
      *(short8*)(sK + r * 256 + ((tK_c * 2) ^ ((r & 7) << 4))) = rk[p];
      const int d = p * 32 + tV_d;
      *(short8*)(sV + d * 128 + ((tV_c * 2) ^ ((d & 7) << 4))) = rv[p];
    }
    __syncthreads();

    if (kt + 1 < NT) {                     // prefetch next tile (overlaps MFMA)
      const int kb = (kt + 1) * 64;
#pragma unroll
      for (int p = 0; p < 4; ++p) {
        rk[p] = *(const short8*)(Kg + (size_t)(kb + p * 16 + tK_r) * HD + tK_c);
        rv[p] = *(const short8*)(Vg + (size_t)(p * 32 + tV_d) * SEQ + kb + tV_c);
      }
    }

#pragma unroll
    for (int kc = 0; kc < 2; ++kc) {       // two 32-k chunks per tile
      f32x16 sacc;
#pragma unroll
      for (int r = 0; r < 16; ++r) sacc[r] = 0.f;
      const int krow = kc * 32 + l31;
#pragma unroll
      for (int es = 0; es < 8; ++es) {
        short8 ka = *(const short8*)(sK + krow * 256 + ((es * 32 + hi * 16) ^ kswz));
        sacc = __builtin_amdgcn_mfma_f32_32x32x16_bf16(ka, qf[es], sacc, 0, 0, 0);
      }

      // online softmax; lane holds S^T[k][q]: q = lane&31,
      // k(chunk) = (r&3) + 8*(r>>2) + 4*hi
      float p0[16];
      float cmax = -1e30f;
#pragma unroll
      for (int r = 0; r < 16; ++r) {
        p0[r] = sacc[r] * CSCALE;
        cmax = fmaxf(cmax, p0[r]);
      }
      cmax = fmaxf(cmax, __shfl_xor(cmax, 32, 64));
      if (!__all(cmax - m <= 8.0f)) {      // defer-max (THR=8, exp2 domain)
        const float newm = fmaxf(m, cmax);
        const float sc = __builtin_amdgcn_exp2f(m - newm);
#pragma unroll
        for (int dt = 0; dt < 4; ++dt)
#pragma unroll
          for (int r = 0; r < 16; ++r) oacc[dt][r] *= sc;
        l *= sc;
        m = newm;
      }
      float ls = 0.f;
#pragma unroll
      for (int r = 0; r < 16; ++r) {
        p0[r] = __builtin_amdgcn_exp2f(p0[r] - m);
        ls += p0[r];
      }
      l += ls;

      // P^T -> bf16 B-frags via cvt_pk + permlane32_swap (T12)
      short8 pb[2];
#pragma unroll
      for (int h2 = 0; h2 < 2; ++h2) {
        unsigned a0 = cvt_pk_bf16(p0[8 * h2 + 0], p0[8 * h2 + 1]);
        unsigned a1 = cvt_pk_bf16(p0[8 * h2 + 2], p0[8 * h2 + 3]);
        unsigned b0 = cvt_pk_bf16(p0[8 * h2 + 4], p0[8 * h2 + 5]);
        unsigned b1 = cvt_pk_bf16(p0[8 * h2 + 6], p0[8 * h2 + 7]);
        permswap32(a0, b0);
        permswap32(a1, b1);
        pb[h2] = mk_frag(a0, a1, b0, b1);
      }

      // O^T += V^T * P^T
#pragma unroll
      for (int ks = 0; ks < 2; ++ks) {
#pragma unroll
        for (int dt = 0; dt < 4; ++dt) {
          const int vrow = dt * 32 + l31;
          short8 va = *(const short8*)(sV + vrow * 128 +
                                       ((kc * 64 + ks * 32 + hi * 16) ^ kswz));
          oacc[dt] = __builtin_amdgcn_mfma_f32_32x32x16_bf16(va, pb[ks], oacc[dt], 0, 0, 0);
        }
      }
    }
  }

  // epilogue: O[q][d] = O^T/lsum ; lane q = lane&31, d = (r&3)+8*(r>>2)+4*hi+32*dt
  const float lt  = l + __shfl_xor(l, 32, 64);
  const float inv = 1.0f / lt;
  float* op = out + ((size_t)b * SEQ + qrow) * HD;
#pragma unroll
  for (int dt = 0; dt < 4; ++dt) {
#pragma unroll
    for (int rg = 0; rg < 4; ++rg) {
      float4 v;
      v.x = oacc[dt][rg * 4 + 0] * inv;
      v.y = oacc[dt][rg * 4 + 1] * inv;
      v.z = oacc[dt][rg * 4 + 2] * inv;
      v.w = oacc[dt][rg * 4 + 3] * inv;
      *(float4*)(op + dt * 32 + rg * 8 + hi * 4) = v;
    }
  }
}

// ---------------------------------------------------------------------------
extern "C" void kernel_launch(void* const* d_in, const int* in_sizes, int n_in,
                              void* d_out, int out_size, void* d_ws, size_t ws_size,
                              hipStream_t stream) {
  (void)in_sizes; (void)n_in; (void)out_size; (void)ws_size;
  const float* X  = (const float*)d_in[0];
  const float* Wk = (const float*)d_in[1];
  const float* bk = (const float*)d_in[2];
  const float* Wq = (const float*)d_in[3];
  const float* bq = (const float*)d_in[4];
  const float* Wv = (const float*)d_in[5];
  const float* bv = (const float*)d_in[6];
  float* out = (float*)d_out;

  // ws: Q bf16 [B][S][HD] | K bf16 [B][S][HD] | V^T bf16 [B][HD][S]  (24 MB)
  __hip_bfloat16* Qw = (__hip_bfloat16*)d_ws;
  __hip_bfloat16* Kw = Qw + (size_t)BATCH * SEQ * HD;
  __hip_bfloat16* Vt = Kw + (size_t)BATCH * SEQ * HD;

  qkv_proj_kernel<<<dim3(BATCH * SEQ / 64, 3), 256, 0, stream>>>(
      X, Wq, bq, Wk, bk, Wv, bv, Qw, Kw, Vt);

  fused_attn_kernel<<<dim3(BATCH * (SEQ / 128)), 256, 0, stream>>>(Qw, Kw, Vt, out);
}

// Round 2
// 124.061 us; speedup vs baseline: 1.5706x; 1.5706x over previous
//
#include <hip/hip_runtime.h>
#include <hip/hip_bf16.h>

typedef __attribute__((ext_vector_type(8)))  short  short8;
typedef __attribute__((ext_vector_type(4)))  float  f32x4;
typedef __attribute__((ext_vector_type(16))) float  f32x16;

#define DEVINL static __device__ __forceinline__

constexpr int BATCH = 8;
constexpr int SEQ   = 4096;
constexpr int EMB   = 256;
constexpr int HD    = 128;

// (1/sqrt(HD)) * log2(e): folded into Q at projection time
#define CSCALE 0.1275174475f

DEVINL unsigned cvt_pk_bf16(float lo, float hi) {
  unsigned r;
  asm("v_cvt_pk_bf16_f32 %0, %1, %2" : "=v"(r) : "v"(lo), "v"(hi));
  return r;
}

DEVINL void permswap32(unsigned &a, unsigned &b) {
  asm("v_permlane32_swap_b32 %0, %1" : "+v"(a), "+v"(b));
}

DEVINL short8 mk_frag(unsigned w0, unsigned w1, unsigned w2, unsigned w3) {
  union { unsigned u[4]; short8 s; } t;
  t.u[0] = w0; t.u[1] = w1; t.u[2] = w2; t.u[3] = w3;
  return t.s;
}

// ---------------------------------------------------------------------------
// Kernel 0: convert the three weight matrices to bf16 once.
// Wb layout: [0]=Wq, [1]=Wk, [2]=Wv, each HD*EMB.
// ---------------------------------------------------------------------------
__global__ __launch_bounds__(256) void wconv_kernel(
    const float* __restrict__ Wq, const float* __restrict__ Wk,
    const float* __restrict__ Wv, __hip_bfloat16* __restrict__ Wb)
{
  const int i = blockIdx.x * 256 + threadIdx.x;   // 24576 threads x 4 elems
  const int which = i >> 13;
  const int off = (i & 8191) << 2;
  const float* W = which == 0 ? Wq : which == 1 ? Wk : Wv;
  float4 f = *(const float4*)(W + off);
  unsigned lo = cvt_pk_bf16(f.x, f.y), hi = cvt_pk_bf16(f.z, f.w);
  unsigned long long pk = ((unsigned long long)hi << 32) | (unsigned long long)lo;
  *(unsigned long long*)(Wb + (size_t)which * 32768 + off) = pk;
}

// ---------------------------------------------------------------------------
// Kernel 1: one-pass QKV projection. X read once; Q,K row-major bf16
// (Q pre-scaled by CSCALE); V written transposed Vt[b][h][s] via LDS.
// 512 blocks x 256 thr; block tile 64 rows; 4 waves 2x2; K=256 in 8 slices.
// ---------------------------------------------------------------------------
__global__ __launch_bounds__(256) void qkv_proj_kernel(
    const float* __restrict__ X, const __hip_bfloat16* __restrict__ Wb,
    const float* __restrict__ bq, const float* __restrict__ bk,
    const float* __restrict__ bv,
    __hip_bfloat16* __restrict__ Qw, __hip_bfloat16* __restrict__ Kw,
    __hip_bfloat16* __restrict__ Vt)
{
  alignas(16) __shared__ char sT[128 * 128];   // V transpose: 128 h-rows x 128B

  const int m0   = blockIdx.x * 64;
  const int tid  = threadIdx.x;
  const int wid  = tid >> 6;
  const int lane = tid & 63;
  const int wr   = wid >> 1, wc = wid & 1;
  const int l15  = lane & 15, l4 = lane >> 4;

  f32x4 acc[3][2][4];
#pragma unroll
  for (int w = 0; w < 3; ++w)
#pragma unroll
    for (int qt = 0; qt < 2; ++qt)
#pragma unroll
      for (int nt = 0; nt < 4; ++nt)
#pragma unroll
        for (int r = 0; r < 4; ++r) acc[w][qt][nt][r] = 0.f;

  const int arow = m0 + wr * 32 + l15;
  const int hrow = wc * 64 + l15;

#pragma unroll
  for (int es = 0; es < 8; ++es) {
    const int k0 = es * 32 + l4 * 8;
    short8 af[2];
#pragma unroll
    for (int qt = 0; qt < 2; ++qt) {
      const float* src = X + (size_t)(arow + qt * 16) * EMB + k0;
      float4 f0 = *(const float4*)(src);
      float4 f1 = *(const float4*)(src + 4);
      af[qt] = mk_frag(cvt_pk_bf16(f0.x, f0.y), cvt_pk_bf16(f0.z, f0.w),
                       cvt_pk_bf16(f1.x, f1.y), cvt_pk_bf16(f1.z, f1.w));
    }
#pragma unroll
    for (int w = 0; w < 3; ++w) {
      short8 bf[4];
#pragma unroll
      for (int nt = 0; nt < 4; ++nt)
        bf[nt] = *(const short8*)(Wb + (size_t)w * 32768 +
                                  (size_t)(hrow + nt * 16) * EMB + k0);
#pragma unroll
      for (int qt = 0; qt < 2; ++qt)
#pragma unroll
        for (int nt = 0; nt < 4; ++nt)
          acc[w][qt][nt] = __builtin_amdgcn_mfma_f32_16x16x32_bf16(
              af[qt], bf[nt], acc[w][qt][nt], 0, 0, 0);
    }
  }

  // --- Q (scaled) and K: direct row-major stores ---
#pragma unroll
  for (int w = 0; w < 2; ++w) {
    __hip_bfloat16* dst = w ? Kw : Qw;
    const float* bia = w ? bk : bq;
    const float scale = w ? 1.0f : CSCALE;
#pragma unroll
    for (int qt = 0; qt < 2; ++qt)
#pragma unroll
      for (int nt = 0; nt < 4; ++nt) {
        const int h = wc * 64 + nt * 16 + l15;
        const float bb = bia[h];
        const int srow = m0 + wr * 32 + qt * 16 + l4 * 4;
#pragma unroll
        for (int r = 0; r < 4; ++r)
          dst[(size_t)(srow + r) * HD + h] =
              __float2bfloat16((acc[w][qt][nt][r] + bb) * scale);
      }
  }

  // --- V: stage transposed [h][s] in LDS (swizzled), then coalesced store ---
#pragma unroll
  for (int qt = 0; qt < 2; ++qt)
#pragma unroll
    for (int nt = 0; nt < 4; ++nt) {
      const int h = wc * 64 + nt * 16 + l15;
      const float bb = bv[h];
      const int s_rel = wr * 32 + qt * 16 + l4 * 4;
      unsigned w0 = cvt_pk_bf16(acc[2][qt][nt][0] + bb, acc[2][qt][nt][1] + bb);
      unsigned w1 = cvt_pk_bf16(acc[2][qt][nt][2] + bb, acc[2][qt][nt][3] + bb);
      unsigned long long pk = ((unsigned long long)w1 << 32) | (unsigned long long)w0;
      *(unsigned long long*)(sT + h * 128 + ((s_rel * 2) ^ ((h & 7) << 4))) = pk;
    }
  __syncthreads();
  const int bi = m0 >> 12;
  const int s_base = m0 & (SEQ - 1);
#pragma unroll
  for (int p = 0; p < 4; ++p) {
    const int idx = p * 256 + tid;
    const int h = idx >> 3, slot = idx & 7;
    short8 v = *(const short8*)(sT + h * 128 + ((slot * 16) ^ ((h & 7) << 4)));
    *(short8*)(Vt + ((size_t)bi * HD + h) * SEQ + s_base + slot * 8) = v;
  }
}

// ---------------------------------------------------------------------------
// Kernel 2: flash attention, 512 thr (8 waves), grid 256 (1 block/CU).
// Waves 0-3: even KV tiles; waves 4-7: odd KV tiles; wave w ^ 4 shares q-rows.
// LDS: sK[2] 64x256B, sV[2] 128x256B (V cols padded), 4-bit XOR swizzle.
// Swapped QK^T: lane owns q = lane&31; in-register online softmax; PV swapped.
// Flash merge of the two KV halves via LDS at the end.
// ---------------------------------------------------------------------------
__global__ __launch_bounds__(512, 2) void fused_attn_kernel(
    const __hip_bfloat16* __restrict__ Qw,
    const __hip_bfloat16* __restrict__ Kw,
    const __hip_bfloat16* __restrict__ Vt,
    float* __restrict__ out)
{
  alignas(16) __shared__ char smem[100352];
  // 0:      sK[0] 16KB | 16384: sK[1] 16KB
  // 32768:  sV[0] 32KB | 65536: sV[1] 32KB
  // 98304:  m stats (256 f32) | 99328: l stats (256 f32)
  float* sm_st = (float*)(smem + 98304);
  float* sl_st = (float*)(smem + 99328);

  const int tid  = threadIdx.x;
  const int wid  = tid >> 6;
  const int lane = tid & 63;
  const int l31  = lane & 31;
  const int hi   = lane >> 5;
  const int qg   = wid & 3;
  const int hw   = wid >> 2;

  const int b  = blockIdx.x & 7;           // batch on low bits -> XCD-local K/V
  const int q0 = (blockIdx.x >> 3) * 128;
  const int qrow = q0 + qg * 32 + l31;

  const __hip_bfloat16* Qp = Qw + ((size_t)b * SEQ + qrow) * HD;
  const __hip_bfloat16* Kg = Kw + (size_t)b * SEQ * HD;
  const __hip_bfloat16* Vg = Vt + (size_t)b * HD * SEQ;

  char* sK = smem + hw * 16384;
  char* sV = smem + 32768 + hw * 32768;

  short8 qf[8];
#pragma unroll
  for (int es = 0; es < 8; ++es)
    qf[es] = *(const short8*)(Qp + es * 16 + hi * 8);

  f32x16 oacc[4];
#pragma unroll
  for (int dt = 0; dt < 4; ++dt)
#pragma unroll
    for (int r = 0; r < 16; ++r) oacc[dt][r] = 0.f;

  float m = -1e30f, l = 0.f;

  // staging: threads 0-255 stage half 0 (even tiles), 256-511 half 1 (odd)
  const int hs = tid >> 8;                 // == hw
  const int st = tid & 255;
  const int tK_r = st >> 4, tK_cb = (st & 15) * 16;   // byte col in row
  const int tV_d = st >> 3, tV_cb = (st & 7) * 16;
  char* wKp = smem + hs * 16384;
  char* wVp = smem + 32768 + hs * 32768;

  short8 rk[4], rv[4];
  {
    const int kb = hs * 64;
#pragma unroll
    for (int p = 0; p < 4; ++p) {
      rk[p] = *(const short8*)(Kg + (size_t)(kb + p * 16 + tK_r) * HD + (tK_cb >> 1));
      rv[p] = *(const short8*)(Vg + (size_t)(p * 32 + tV_d) * SEQ + kb + (tV_cb >> 1));
    }
  }

  const int NTH = SEQ / 64 / 2;            // 32 tiles per half

  for (int t = 0; t < NTH; ++t) {
    __syncthreads();
#pragma unroll
    for (int p = 0; p < 4; ++p) {
      const int r = p * 16 + tK_r;
      *(short8*)(wKp + r * 256 + (tK_cb ^ ((r & 15) << 4))) = rk[p];
      const int d = p * 32 + tV_d;
      *(short8*)(wVp + d * 256 + (tV_cb ^ ((d & 15) << 4))) = rv[p];
    }
    __syncthreads();

    if (t + 1 < NTH) {
      const int kb = (2 * (t + 1) + hs) * 64;
#pragma unroll
      for (int p = 0; p < 4; ++p) {
        rk[p] = *(const short8*)(Kg + (size_t)(kb + p * 16 + tK_r) * HD + (tK_cb >> 1));
        rv[p] = *(const short8*)(Vg + (size_t)(p * 32 + tV_d) * SEQ + kb + (tV_cb >> 1));
      }
    }

#pragma unroll
    for (int kc = 0; kc < 2; ++kc) {
      f32x16 sacc;
#pragma unroll
      for (int r = 0; r < 16; ++r) sacc[r] = 0.f;
      const int krow = kc * 32 + l31;
      const unsigned kkey = (unsigned)((krow & 15) << 4);
      __builtin_amdgcn_s_setprio(1);
#pragma unroll
      for (int es = 0; es < 8; ++es) {
        short8 ka = *(const short8*)(sK + krow * 256 + ((es * 32 + hi * 16) ^ kkey));
        sacc = __builtin_amdgcn_mfma_f32_32x32x16_bf16(ka, qf[es], sacc, 0, 0, 0);
      }
      __builtin_amdgcn_s_setprio(0);

      // online softmax (scores pre-scaled; exp2 domain)
      float p0[16];
      float cmax = -1e30f;
#pragma unroll
      for (int r = 0; r < 16; ++r) {
        p0[r] = sacc[r];
        cmax = fmaxf(cmax, p0[r]);
      }
      cmax = fmaxf(cmax, __shfl_xor(cmax, 32, 64));
      if (!__all(cmax - m <= 8.0f)) {      // defer-max (THR=8)
        const float newm = fmaxf(m, cmax);
        const float sc = __builtin_amdgcn_exp2f(m - newm);
#pragma unroll
        for (int dt = 0; dt < 4; ++dt)
#pragma unroll
          for (int r = 0; r < 16; ++r) oacc[dt][r] *= sc;
        l *= sc;
        m = newm;
      }
      float ls = 0.f;
#pragma unroll
      for (int r = 0; r < 16; ++r) {
        p0[r] = __builtin_amdgcn_exp2f(p0[r] - m);
        ls += p0[r];
      }
      l += ls;

      // P^T -> bf16 B-frags via cvt_pk + permlane32_swap
      short8 pb[2];
#pragma unroll
      for (int h2 = 0; h2 < 2; ++h2) {
        unsigned a0 = cvt_pk_bf16(p0[8 * h2 + 0], p0[8 * h2 + 1]);
        unsigned a1 = cvt_pk_bf16(p0[8 * h2 + 2], p0[8 * h2 + 3]);
        unsigned b0 = cvt_pk_bf16(p0[8 * h2 + 4], p0[8 * h2 + 5]);
        unsigned b1 = cvt_pk_bf16(p0[8 * h2 + 6], p0[8 * h2 + 7]);
        permswap32(a0, b0);
        permswap32(a1, b1);
        pb[h2] = mk_frag(a0, a1, b0, b1);
      }

      __builtin_amdgcn_s_setprio(1);
#pragma unroll
      for (int ks = 0; ks < 2; ++ks) {
#pragma unroll
        for (int dt = 0; dt < 4; ++dt) {
          const int vrow = dt * 32 + l31;
          const unsigned vkey = (unsigned)((vrow & 15) << 4);
          short8 va = *(const short8*)(sV + vrow * 256 +
                                       ((kc * 64 + ks * 32 + hi * 16) ^ vkey));
          oacc[dt] = __builtin_amdgcn_mfma_f32_32x32x16_bf16(va, pb[ks], oacc[dt], 0, 0, 0);
        }
      }
      __builtin_amdgcn_s_setprio(0);
    }
  }

  // ---- flash merge of the two halves (wave w <-> w^4) ----
  const float ltot = l + __shfl_xor(l, 32, 64);
  if (hi == 0) { sm_st[wid * 32 + l31] = m; sl_st[wid * 32 + l31] = ltot; }
  __syncthreads();                          // also: all LDS tile reads done
  const int pw = wid ^ 4;
  const float m2 = sm_st[pw * 32 + l31];
  const float l2 = sl_st[pw * 32 + l31];
  const float M  = fmaxf(m, m2);
  const float aown = __builtin_amdgcn_exp2f(m - M);
  const float Ltot = ltot * aown + l2 * __builtin_amdgcn_exp2f(m2 - M);

  float* mb = (float*)smem + (size_t)qg * 4096;   // [128 d][32 q] f32, 16KB/group
  if (hw == 1) {
#pragma unroll
    for (int dt = 0; dt < 4; ++dt)
#pragma unroll
      for (int r = 0; r < 16; ++r) {
        const int d = dt * 32 + (r & 3) + 8 * (r >> 2) + 4 * hi;
        mb[d * 32 + l31] = oacc[dt][r] * aown;
      }
  }
  __syncthreads();
  if (hw == 0) {
    const float inv = 1.0f / Ltot;
    float* op = out + ((size_t)b * SEQ + qrow) * HD;
#pragma unroll
    for (int dt = 0; dt < 4; ++dt) {
#pragma unroll
      for (int rg = 0; rg < 4; ++rg) {
        const int d0 = dt * 32 + rg * 8 + hi * 4;
        float4 v;
        v.x = (oacc[dt][rg * 4 + 0] * aown + mb[(d0 + 0) * 32 + l31]) * inv;
        v.y = (oacc[dt][rg * 4 + 1] * aown + mb[(d0 + 1) * 32 + l31]) * inv;
        v.z = (oacc[dt][rg * 4 + 2] * aown + mb[(d0 + 2) * 32 + l31]) * inv;
        v.w = (oacc[dt][rg * 4 + 3] * aown + mb[(d0 + 3) * 32 + l31]) * inv;
        *(float4*)(op + d0) = v;
      }
    }
  }
}

// ---------------------------------------------------------------------------
extern "C" void kernel_launch(void* const* d_in, const int* in_sizes, int n_in,
                              void* d_out, int out_size, void* d_ws, size_t ws_size,
                              hipStream_t stream) {
  (void)in_sizes; (void)n_in; (void)out_size; (void)ws_size;
  const float* X  = (const float*)d_in[0];
  const float* Wk = (const float*)d_in[1];
  const float* bk = (const float*)d_in[2];
  const float* Wq = (const float*)d_in[3];
  const float* bq = (const float*)d_in[4];
  const float* Wv = (const float*)d_in[5];
  const float* bv = (const float*)d_in[6];
  float* out = (float*)d_out;

  // ws: Q bf16 [B][S][HD] | K bf16 | V^T bf16 [B][HD][S] | Wb bf16 [3][HD][EMB]
  __hip_bfloat16* Qw = (__hip_bfloat16*)d_ws;
  __hip_bfloat16* Kw = Qw + (size_t)BATCH * SEQ * HD;
  __hip_bfloat16* Vt = Kw + (size_t)BATCH * SEQ * HD;
  __hip_bfloat16* Wb = Vt + (size_t)BATCH * SEQ * HD;

  wconv_kernel<<<96, 256, 0, stream>>>(Wq, Wk, Wv, Wb);
  qkv_proj_kernel<<<BATCH * SEQ / 64, 256, 0, stream>>>(
      X, Wb, bq, bk, bv, Qw, Kw, Vt);
  fused_attn_kernel<<<BATCH * (SEQ / 128), 512, 0, stream>>>(Qw, Kw, Vt, out);
}